// Round 1
// baseline (299.412 us; speedup 1.0000x reference)
//
#include <hip/hip_runtime.h>
#include <hip/hip_bf16.h>
#include <stdint.h>

#define B_   2048
#define P_   20
#define D_   64
#define V_   100000
#define T_   33
#define FIN  2240          // 35*64
#define M_   (B_*P_)       // 40960
#define H1_  512
#define H2_  256

using bf16 = __hip_bfloat16;
typedef __bf16 bf16x8 __attribute__((ext_vector_type(8)));
typedef float  f32x4  __attribute__((ext_vector_type(4)));

__device__ __forceinline__ unsigned short f2b(float f) {
    bf16 h = __float2bfloat16(f);
    return __builtin_bit_cast(unsigned short, h);
}

__device__ __forceinline__ void gload16(const void* g, void* l) {
    __builtin_amdgcn_global_load_lds(
        (const __attribute__((address_space(1))) uint32_t*)g,
        (__attribute__((address_space(3))) uint32_t*)l, 16, 0, 0);
}

// ---------------------------------------------------------------------------
// Kernel 1: build feat (M x FIN) bf16.  k<128: raw broadcast; else emb gather.
// One thread = 4 consecutive feat elements (float4 read, ushort4 write).
// ---------------------------------------------------------------------------
__global__ __launch_bounds__(256) void build_feat_k(
    const float* __restrict__ x_raw, const int* __restrict__ x_idx,
    const float* __restrict__ emb, bf16* __restrict__ feat)
{
    int tid = blockIdx.x * 256 + threadIdx.x;
    int m = tid / 560;                 // 560 = FIN/4
    if (m >= M_) return;
    int r  = tid - m * 560;
    int k0 = r << 2;
    int blk = k0 >> 6;                 // 0..34
    float4 v;
    if (blk < 2) {
        float x = x_raw[m * 2 + blk];
        v = make_float4(x, x, x, x);
    } else {
        int t  = blk - 2;
        int vi = x_idx[m * T_ + t];
        const float4* src = reinterpret_cast<const float4*>(
            emb + ((size_t)t * V_ + (size_t)vi) * D_ + (k0 & 63));
        v = *src;
    }
    ushort4 o;
    o.x = f2b(v.x); o.y = f2b(v.y); o.z = f2b(v.z); o.w = f2b(v.w);
    *reinterpret_cast<ushort4*>(feat + (size_t)m * FIN + k0) = o;
}

// ---------------------------------------------------------------------------
// Kernel 2: W (K x N fp32, row-major) -> Wt (N x K bf16, row-major).
// Thread per OUTPUT element (coalesced 2B writes; reads served by L2/L3).
// ---------------------------------------------------------------------------
__global__ __launch_bounds__(256) void transpose_bf16_k(
    const float* __restrict__ W, bf16* __restrict__ Wt, int K, int N)
{
    int idx = blockIdx.x * 256 + threadIdx.x;
    if (idx >= N * K) return;
    int n = idx / K;
    int k = idx - n * K;
    Wt[idx] = __float2bfloat16(W[(size_t)k * N + n]);
}

// ---------------------------------------------------------------------------
// Kernel 3: bf16 MFMA GEMM  C(MxN) = relu(A(MxK) @ B + bias)
//   A row-major bf16, Bt = B^T row-major (N x K) bf16.
//   128x128 tile, BK=32, 256 thr = 4 waves (2x2), each wave 64x64 (4x4 frags
//   of mfma_f32_16x16x32_bf16).  global_load_lds width 16, 2-barrier K loop.
//   Block swizzle: XCD-chunked so same-M tiles share one XCD's L2.
// ---------------------------------------------------------------------------
__device__ __forceinline__ void store1(float* p, float v) { *p = v; }
__device__ __forceinline__ void store1(bf16*  p, float v) { *p = __float2bfloat16(v); }

template<typename OUT_T>
__global__ __launch_bounds__(256) void gemm_rrt_k(
    const bf16* __restrict__ A, const bf16* __restrict__ Bt,
    const float* __restrict__ bias, OUT_T* __restrict__ C,
    int M, int N, int K, int NT, int chunk)
{
    __shared__ bf16 lsA[128 * 32];
    __shared__ bf16 lsB[128 * 32];

    int bid = blockIdx.x;
    int wg  = (bid & 7) * chunk + (bid >> 3);   // bijective: nwg % 8 == 0
    int mt  = wg / NT, nt = wg - mt * NT;
    int m0  = mt * 128, n0 = nt * 128;

    int tid = threadIdx.x;
    int l = tid & 63, w = tid >> 6;
    int wr = w >> 1, wc = w & 1;
    int fr = l & 15, fq = l >> 4;

    f32x4 acc[4][4] = {};

    // staging geometry: wave w covers rows [w*16 + l/4] (j=0) and +64 (j=1)
    int arow = w * 16 + (l >> 2);
    int acol = (l & 3) * 8;
    const bf16* gA = A  + (size_t)(m0 + arow) * K + acol;
    const bf16* gB = Bt + (size_t)(n0 + arow) * K + acol;
    char* lA = (char*)lsA + w * 1024;   // HW adds lane*16
    char* lB = (char*)lsB + w * 1024;

    int nk = K >> 5;
    for (int kt = 0; kt < nk; ++kt) {
        gload16(gA,                 lA);
        gload16(gA + (size_t)64*K,  lA + 4096);
        gload16(gB,                 lB);
        gload16(gB + (size_t)64*K,  lB + 4096);
        gA += 32; gB += 32;
        __syncthreads();   // compiler drains vmcnt before barrier

        bf16x8 af[4], bg[4];
        #pragma unroll
        for (int i = 0; i < 4; ++i)
            af[i] = *reinterpret_cast<const bf16x8*>(&lsA[(wr*64 + i*16 + fr)*32 + fq*8]);
        #pragma unroll
        for (int j = 0; j < 4; ++j)
            bg[j] = *reinterpret_cast<const bf16x8*>(&lsB[(wc*64 + j*16 + fr)*32 + fq*8]);
        #pragma unroll
        for (int i = 0; i < 4; ++i)
            #pragma unroll
            for (int j = 0; j < 4; ++j)
                acc[i][j] = __builtin_amdgcn_mfma_f32_16x16x32_bf16(
                    af[i], bg[j], acc[i][j], 0, 0, 0);
        __syncthreads();   // all reads done before next stage
    }

    #pragma unroll
    for (int j = 0; j < 4; ++j) {
        int col = n0 + wc*64 + j*16 + fr;
        float bv = bias[col];
        #pragma unroll
        for (int i = 0; i < 4; ++i) {
            int row0 = m0 + wr*64 + i*16 + fq*4;
            #pragma unroll
            for (int r2 = 0; r2 < 4; ++r2) {
                float v = acc[i][j][r2] + bv;
                v = fmaxf(v, 0.0f);
                store1(&C[(size_t)(row0 + r2) * N + col], v);
            }
        }
    }
}

// ---------------------------------------------------------------------------
// Kernel 4: head — logits = h2 @ W3 + b3, softmax over P=20.  Block per b.
// ---------------------------------------------------------------------------
__global__ __launch_bounds__(256) void head_k(
    const float* __restrict__ h2, const float* __restrict__ W3,
    const float* __restrict__ b3, float* __restrict__ out)
{
    int b = blockIdx.x;
    int w = threadIdx.x >> 6, l = threadIdx.x & 63;
    __shared__ float w3s[H2_];
    __shared__ float logits[P_];
    w3s[threadIdx.x] = W3[threadIdx.x];
    __syncthreads();

    for (int p = w; p < P_; p += 4) {
        const float4 hv = *reinterpret_cast<const float4*>(
            h2 + ((size_t)b * P_ + p) * H2_ + l * 4);
        const float4 wv = *reinterpret_cast<const float4*>(&w3s[l * 4]);
        float s = hv.x*wv.x + hv.y*wv.y + hv.z*wv.z + hv.w*wv.w;
        #pragma unroll
        for (int off = 32; off; off >>= 1) s += __shfl_down(s, off);
        if (l == 0) logits[p] = s + b3[0];
    }
    __syncthreads();

    if (threadIdx.x < P_) {
        float mx = -1e30f;
        #pragma unroll
        for (int p = 0; p < P_; ++p) mx = fmaxf(mx, logits[p]);
        float sum = 0.0f;
        #pragma unroll
        for (int p = 0; p < P_; ++p) sum += expf(logits[p] - mx);
        out[(size_t)b * P_ + threadIdx.x] = expf(logits[threadIdx.x] - mx) / sum;
    }
}

// ---------------------------------------------------------------------------
extern "C" void kernel_launch(void* const* d_in, const int* in_sizes, int n_in,
                              void* d_out, int out_size, void* d_ws, size_t ws_size,
                              hipStream_t stream)
{
    const float* x_raw = (const float*)d_in[0];
    const int*   x_idx = (const int*)  d_in[1];
    const float* emb   = (const float*)d_in[2];
    const float* W1    = (const float*)d_in[3];
    const float* b1    = (const float*)d_in[4];
    const float* W2    = (const float*)d_in[5];
    const float* b2    = (const float*)d_in[6];
    const float* W3    = (const float*)d_in[7];
    const float* b3    = (const float*)d_in[8];

    char* ws = (char*)d_ws;
    size_t off = 0;
    bf16* feat = (bf16*)(ws + off); off += (size_t)M_ * FIN * 2;   // 183.5 MB
    bf16* W1t  = (bf16*)(ws + off); off += (size_t)H1_ * FIN * 2;  // 2.3 MB
    bf16* W2t  = (bf16*)(ws + off); off += (size_t)H2_ * H1_ * 2;  // 0.26 MB
    bf16* h1   = (bf16*)(ws + off); off += (size_t)M_ * H1_ * 2;   // 42 MB
    float* h2  = (float*)(ws + off); off += (size_t)M_ * H2_ * 4;  // 42 MB

    // 1) gather/build feat: M_*FIN/4 threads
    build_feat_k<<<(M_ * (FIN/4) + 255) / 256, 256, 0, stream>>>(x_raw, x_idx, emb, feat);

    // 2) weight transpose+convert
    transpose_bf16_k<<<(H1_ * FIN + 255) / 256, 256, 0, stream>>>(W1, W1t, FIN, H1_);
    transpose_bf16_k<<<(H2_ * H1_ + 255) / 256, 256, 0, stream>>>(W2, W2t, H1_, H2_);

    // 3) GEMM1: (40960 x 2240) @ (2240 x 512) -> h1 bf16, relu
    //    grid 320*4 = 1280, chunk = 1280/8 = 160
    gemm_rrt_k<bf16><<<1280, 256, 0, stream>>>(feat, W1t, b1, h1, M_, H1_, FIN, 4, 160);

    // 4) GEMM2: (40960 x 512) @ (512 x 256) -> h2 fp32, relu
    //    grid 320*2 = 640, chunk = 80
    gemm_rrt_k<float><<<640, 256, 0, stream>>>(h1, W2t, b2, h2, M_, H2_, H1_, 2, 80);

    // 5) head: GEMV + softmax over P
    head_k<<<B_, 256, 0, stream>>>(h2, W3, b3, (float*)d_out);
}

// Round 2
// 285.942 us; speedup vs baseline: 1.0471x; 1.0471x over previous
//
#include <hip/hip_runtime.h>
#include <hip/hip_bf16.h>
#include <stdint.h>

#define B_   2048
#define P_   20
#define D_   64
#define V_   100000
#define T_   33
#define FIN  2240          // 35*64
#define KE   2112          // 33*64  (emb-only K; raw cols folded into epilogue)
#define M_   (B_*P_)       // 40960
#define H1_  512
#define H2_  256

using bf16 = __hip_bfloat16;
typedef __bf16 bf16x8 __attribute__((ext_vector_type(8)));
typedef float  f32x4  __attribute__((ext_vector_type(4)));

__device__ __forceinline__ unsigned short f2b(float f) {
    bf16 h = __float2bfloat16(f);
    return __builtin_bit_cast(unsigned short, h);
}

__device__ __forceinline__ void gload16(const void* g, void* l) {
    __builtin_amdgcn_global_load_lds(
        (const __attribute__((address_space(1))) uint32_t*)g,
        (__attribute__((address_space(3))) uint32_t*)l, 16, 0, 0);
}

// ---------------------------------------------------------------------------
// prep 1: column sums of W1 rows 0..63 (S0) and 64..127 (S1).  S01 = [S0|S1]
// ---------------------------------------------------------------------------
__global__ __launch_bounds__(256) void colsum_k(
    const float* __restrict__ W1, float* __restrict__ S01)
{
    int n = blockIdx.x * 256 + threadIdx.x;
    if (n >= H1_) return;
    float s0 = 0.f, s1 = 0.f;
    for (int k = 0; k < 64; ++k)  s0 += W1[(size_t)k * H1_ + n];
    for (int k = 64; k < 128; ++k) s1 += W1[(size_t)k * H1_ + n];
    S01[n] = s0;
    S01[H1_ + n] = s1;
}

// ---------------------------------------------------------------------------
// prep 2: W1 rows 128.. -> W1t (512 x 2112) bf16 row-major (transposed)
// ---------------------------------------------------------------------------
__global__ __launch_bounds__(256) void w1t_k(
    const float* __restrict__ W1, bf16* __restrict__ W1t)
{
    int idx = blockIdx.x * 256 + threadIdx.x;   // n*KE + k
    int n = idx / KE;
    int k = idx - n * KE;
    W1t[idx] = __float2bfloat16(W1[(size_t)(k + 128) * H1_ + n]);
}

// ---------------------------------------------------------------------------
// prep 3: generic W (K x N fp32) -> Wt (N x K bf16)
// ---------------------------------------------------------------------------
__global__ __launch_bounds__(256) void transpose_bf16_k(
    const float* __restrict__ W, bf16* __restrict__ Wt, int K, int N)
{
    int idx = blockIdx.x * 256 + threadIdx.x;
    if (idx >= N * K) return;
    int n = idx / K;
    int k = idx - n * K;
    Wt[idx] = __float2bfloat16(W[(size_t)k * N + n]);
}

// ---------------------------------------------------------------------------
// FUSED gather + GEMM1:  h1 = relu(feat @ W1 + b1)
//   grid 256 (BM=160, exactly 1 block/CU), 512 thr = 8 waves (2x4),
//   wave tile 80x128, BN=512 (full N -> each emb row gathered ONCE),
//   BK=64 (one emb block per K-tile).
//   A: reg-staged gather (fp32->bf16), XOR-swizzled LDS [160][64].
//   B: global_load_lds w16, double-buffered, source pre-swizzled.
//   Raw feature cols (rank-2) folded into epilogue via S0/S1.
// ---------------------------------------------------------------------------
__global__ __launch_bounds__(512, 2) void fused_gemm1_k(
    const float* __restrict__ x_raw, const int* __restrict__ x_idx,
    const float* __restrict__ emb, const bf16* __restrict__ W1t,
    const float* __restrict__ b1, const float* __restrict__ S01,
    bf16* __restrict__ h1)
{
    extern __shared__ char smem[];
    char* Als = smem;            // [160][64] bf16, swizzled, 20480 B
    char* Bls = smem + 20480;    // 2 x [512][64] bf16, swizzled, 2 x 65536 B

    const int tid = threadIdx.x;
    const int w  = tid >> 6, l = tid & 63;
    const int wr = w >> 2, wc = w & 3;         // 2 x 4 wave grid
    const int fr = l & 15, fq = l >> 4;
    const int m0 = blockIdx.x * 160;

    // A staging role: row r = p*32 + arow, 16 lanes per row (cols ali*4..+3)
    const int arow = tid >> 4;                 // 0..31
    const int ali  = tid & 15;

    // B staging role (per wave, q=0..7): dest o = q*8192 + w*1024 + 16*l
    //   row n = q*64 + w*8 + (l>>3); swizzled source col = 8*((l&7)^(l>>3))
    const int bn   = w * 8 + (l >> 3);
    const int bcol = 8 * ((l & 7) ^ (l >> 3));

    f32x4  acc[5][8] = {};
    float4 areg[5];
    int    ivi[5];

    auto load_idx = [&](int t) {
        #pragma unroll
        for (int p = 0; p < 5; ++p)
            ivi[p] = x_idx[(size_t)(m0 + p * 32 + arow) * T_ + t];
    };
    auto issue_A = [&](int t) {
        #pragma unroll
        for (int p = 0; p < 5; ++p)
            areg[p] = *reinterpret_cast<const float4*>(
                emb + ((size_t)t * V_ + (size_t)ivi[p]) * D_ + ali * 4);
    };
    auto issue_B = [&](int kt, int buf) {
        char* base = Bls + buf * 65536 + w * 1024;
        #pragma unroll
        for (int q = 0; q < 8; ++q)
            gload16(W1t + (size_t)(q * 64 + bn) * KE + kt * 64 + bcol,
                    base + q * 8192);
    };
    auto write_A = [&]() {
        #pragma unroll
        for (int p = 0; p < 5; ++p) {
            int r = p * 32 + arow;
            ushort4 o;
            o.x = f2b(areg[p].x); o.y = f2b(areg[p].y);
            o.z = f2b(areg[p].z); o.w = f2b(areg[p].w);
            int byte = (r * 128 + ali * 8) ^ ((r & 7) << 4);
            *reinterpret_cast<ushort4*>(Als + byte) = o;
        }
    };

    // prologue
    load_idx(0);
    issue_A(0);
    issue_B(0, 0);
    load_idx(1);

    int cur = 0;
    const int NKT = KE / 64;   // 33
    for (int kt = 0; kt < NKT; ++kt) {
        write_A();                        // A(kt) regs -> LDS
        __syncthreads();                  // drains vmcnt: B(kt) complete
        if (kt + 1 < NKT) {
            issue_A(kt + 1);              // gather next emb block (regs)
            issue_B(kt + 1, cur ^ 1);     // next W1 tile (async -> LDS)
        }
        if (kt + 2 < NKT) load_idx(kt + 2);

        char* Bbase = Bls + cur * 65536;
        #pragma unroll
        for (int kk = 0; kk < 2; ++kk) {
            bf16x8 af[5];
            #pragma unroll
            for (int i = 0; i < 5; ++i) {
                int r = wr * 80 + i * 16 + fr;
                int byte = (r * 128 + kk * 64 + fq * 16) ^ ((r & 7) << 4);
                af[i] = *reinterpret_cast<const bf16x8*>(Als + byte);
            }
            #pragma unroll
            for (int j = 0; j < 8; ++j) {
                int n = wc * 128 + j * 16 + fr;
                int byte = (n * 128 + kk * 64 + fq * 16) ^ ((n & 7) << 4);
                bf16x8 bg = *reinterpret_cast<const bf16x8*>(Bbase + byte);
                #pragma unroll
                for (int i = 0; i < 5; ++i)
                    acc[i][j] = __builtin_amdgcn_mfma_f32_16x16x32_bf16(
                        af[i], bg, acc[i][j], 0, 0, 0);
            }
        }
        __syncthreads();                  // Als reads done; next tile may rewrite
        cur ^= 1;
    }

    // epilogue: bias + rank-2 raw contribution + relu -> h1 (bf16)
    const float* S0 = S01;
    const float* S1 = S01 + H1_;
    #pragma unroll
    for (int i = 0; i < 5; ++i) {
        int rbase = wr * 80 + i * 16 + fq * 4;
        float x0[4], x1[4];
        #pragma unroll
        for (int r2 = 0; r2 < 4; ++r2) {
            int m = m0 + rbase + r2;
            x0[r2] = x_raw[2 * m];
            x1[r2] = x_raw[2 * m + 1];
        }
        #pragma unroll
        for (int j = 0; j < 8; ++j) {
            int n = wc * 128 + j * 16 + fr;
            float bb = b1[n], s0 = S0[n], s1 = S1[n];
            #pragma unroll
            for (int r2 = 0; r2 < 4; ++r2) {
                float v = acc[i][j][r2] + bb + x0[r2] * s0 + x1[r2] * s1;
                h1[(size_t)(m0 + rbase + r2) * H1_ + n] =
                    __float2bfloat16(fmaxf(v, 0.0f));
            }
        }
    }
}

// ---------------------------------------------------------------------------
// GEMM2 (unchanged structure): C = relu(A @ B + bias), 128x128 tile, BK=32
// ---------------------------------------------------------------------------
__device__ __forceinline__ void store1(float* p, float v) { *p = v; }
__device__ __forceinline__ void store1(bf16*  p, float v) { *p = __float2bfloat16(v); }

template<typename OUT_T>
__global__ __launch_bounds__(256) void gemm_rrt_k(
    const bf16* __restrict__ A, const bf16* __restrict__ Bt,
    const float* __restrict__ bias, OUT_T* __restrict__ C,
    int M, int N, int K, int NT, int chunk)
{
    __shared__ bf16 lsA[128 * 32];
    __shared__ bf16 lsB[128 * 32];

    int bid = blockIdx.x;
    int wg  = (bid & 7) * chunk + (bid >> 3);
    int mt  = wg / NT, nt = wg - mt * NT;
    int m0  = mt * 128, n0 = nt * 128;

    int tid = threadIdx.x;
    int l = tid & 63, w = tid >> 6;
    int wr = w >> 1, wc = w & 1;
    int fr = l & 15, fq = l >> 4;

    f32x4 acc[4][4] = {};

    int arow = w * 16 + (l >> 2);
    int acol = (l & 3) * 8;
    const bf16* gA = A  + (size_t)(m0 + arow) * K + acol;
    const bf16* gB = Bt + (size_t)(n0 + arow) * K + acol;
    char* lA = (char*)lsA + w * 1024;
    char* lB = (char*)lsB + w * 1024;

    int nk = K >> 5;
    for (int kt = 0; kt < nk; ++kt) {
        gload16(gA,                lA);
        gload16(gA + (size_t)64*K, lA + 4096);
        gload16(gB,                lB);
        gload16(gB + (size_t)64*K, lB + 4096);
        gA += 32; gB += 32;
        __syncthreads();

        bf16x8 af[4], bg[4];
        #pragma unroll
        for (int i = 0; i < 4; ++i)
            af[i] = *reinterpret_cast<const bf16x8*>(&lsA[(wr*64 + i*16 + fr)*32 + fq*8]);
        #pragma unroll
        for (int j = 0; j < 4; ++j)
            bg[j] = *reinterpret_cast<const bf16x8*>(&lsB[(wc*64 + j*16 + fr)*32 + fq*8]);
        #pragma unroll
        for (int i = 0; i < 4; ++i)
            #pragma unroll
            for (int j = 0; j < 4; ++j)
                acc[i][j] = __builtin_amdgcn_mfma_f32_16x16x32_bf16(
                    af[i], bg[j], acc[i][j], 0, 0, 0);
        __syncthreads();
    }

    #pragma unroll
    for (int j = 0; j < 4; ++j) {
        int col = n0 + wc*64 + j*16 + fr;
        float bv = bias[col];
        #pragma unroll
        for (int i = 0; i < 4; ++i) {
            int row0 = m0 + wr*64 + i*16 + fq*4;
            #pragma unroll
            for (int r2 = 0; r2 < 4; ++r2) {
                float v = acc[i][j][r2] + bv;
                v = fmaxf(v, 0.0f);
                store1(&C[(size_t)(row0 + r2) * N + col], v);
            }
        }
    }
}

// ---------------------------------------------------------------------------
// head: logits = h2 @ W3 + b3, softmax over P=20.  Block per batch b.
// ---------------------------------------------------------------------------
__global__ __launch_bounds__(256) void head_k(
    const float* __restrict__ h2, const float* __restrict__ W3,
    const float* __restrict__ b3, float* __restrict__ out)
{
    int b = blockIdx.x;
    int w = threadIdx.x >> 6, l = threadIdx.x & 63;
    __shared__ float w3s[H2_];
    __shared__ float logits[P_];
    w3s[threadIdx.x] = W3[threadIdx.x];
    __syncthreads();

    for (int p = w; p < P_; p += 4) {
        const float4 hv = *reinterpret_cast<const float4*>(
            h2 + ((size_t)b * P_ + p) * H2_ + l * 4);
        const float4 wv = *reinterpret_cast<const float4*>(&w3s[l * 4]);
        float s = hv.x*wv.x + hv.y*wv.y + hv.z*wv.z + hv.w*wv.w;
        #pragma unroll
        for (int off = 32; off; off >>= 1) s += __shfl_down(s, off);
        if (l == 0) logits[p] = s + b3[0];
    }
    __syncthreads();

    if (threadIdx.x < P_) {
        float mx = -1e30f;
        #pragma unroll
        for (int p = 0; p < P_; ++p) mx = fmaxf(mx, logits[p]);
        float sum = 0.0f;
        #pragma unroll
        for (int p = 0; p < P_; ++p) sum += expf(logits[p] - mx);
        out[(size_t)b * P_ + threadIdx.x] = expf(logits[threadIdx.x] - mx) / sum;
    }
}

// ---------------------------------------------------------------------------
extern "C" void kernel_launch(void* const* d_in, const int* in_sizes, int n_in,
                              void* d_out, int out_size, void* d_ws, size_t ws_size,
                              hipStream_t stream)
{
    const float* x_raw = (const float*)d_in[0];
    const int*   x_idx = (const int*)  d_in[1];
    const float* emb   = (const float*)d_in[2];
    const float* W1    = (const float*)d_in[3];
    const float* b1    = (const float*)d_in[4];
    const float* W2    = (const float*)d_in[5];
    const float* b2    = (const float*)d_in[6];
    const float* W3    = (const float*)d_in[7];
    const float* b3    = (const float*)d_in[8];

    char* ws = (char*)d_ws;
    size_t off = 0;
    bf16*  W1t = (bf16*) (ws + off); off += (size_t)H1_ * KE * 2;    // 2.16 MB
    bf16*  W2t = (bf16*) (ws + off); off += (size_t)H2_ * H1_ * 2;   // 0.26 MB
    float* S01 = (float*)(ws + off); off += (size_t)2 * H1_ * 4;     // 4 KB
    bf16*  h1  = (bf16*) (ws + off); off += (size_t)M_ * H1_ * 2;    // 42 MB
    float* h2  = (float*)(ws + off); off += (size_t)M_ * H2_ * 4;    // 42 MB

    // prep
    colsum_k<<<2, 256, 0, stream>>>(W1, S01);
    w1t_k<<<(H1_ * KE) / 256, 256, 0, stream>>>(W1, W1t);
    transpose_bf16_k<<<(H2_ * H1_ + 255) / 256, 256, 0, stream>>>(W2, W2t, H1_, H2_);

    // fused gather + GEMM1 (148 KB dynamic LDS)
    hipFuncSetAttribute((const void*)fused_gemm1_k,
                        hipFuncAttributeMaxDynamicSharedMemorySize, 151552);
    fused_gemm1_k<<<256, 512, 151552, stream>>>(x_raw, x_idx, emb, W1t, b1, S01, h1);

    // GEMM2: (40960 x 512) @ (512 x 256) -> h2 fp32, relu
    gemm_rrt_k<float><<<640, 256, 0, stream>>>(h1, W2t, b2, h2, M_, H2_, H1_, 2, 80);

    // head
    head_k<<<B_, 256, 0, stream>>>(h2, W3, b3, (float*)d_out);
}